// Round 7
// baseline (410.076 us; speedup 1.0000x reference)
//
#include <hip/hip_runtime.h>
#include <hip/hip_bf16.h>
#include <math.h>

// ExpertPool: B=2,N=1024 -> T=2048 tokens, D=768, E=8, H=3072, top-K=2
#define T_TOK 2048
#define DIM   768
#define NEXP  8
#define HDIM  3072
#define MAXP  (T_TOK * 2)   // exactly 4096 (token,expert) pairs
#define LDST  40            // LDS row stride in ushorts (80 B)
#define NTILE_MAX 40        // sum ceil(cnt_e/128) <= 39

typedef __attribute__((ext_vector_type(8))) short bfrag;   // 8 bf16 (4 VGPRs)
typedef __attribute__((ext_vector_type(4))) float f32x4;   // MFMA C/D

__device__ __forceinline__ unsigned short f2bf(float f) {
  union { float f; unsigned int u; } x; x.f = f;
  unsigned int r = x.u + 0x7fffu + ((x.u >> 16) & 1u);  // RNE
  return (unsigned short)(r >> 16);
}

// ---- fused prep: block 0 = routing; blocks 1.. = fp32->bf16 streaming convert.
//      r6 lesson: 28k tiny blocks ran at 1.9 TB/s (launch-rate/MLP-limited).
//      Now 1776 fat blocks x 32K floats, loads batched 8-deep per group.
//      Block ranges (exact): X=48, Wg=576, Wv=576, Wo=576.
__global__ void k_prep(const float* __restrict__ disp,
                       const float* __restrict__ comb,
                       int* __restrict__ meta,        // [0..7]=cnt [8..15]=off [16]=ntiles [17..56]=tiles
                       float* __restrict__ row_comb,
                       int* __restrict__ row_token,
                       int* __restrict__ tok2pair,    // (T_TOK,2)
                       const float* __restrict__ X, unsigned short* __restrict__ Xb,
                       const float* __restrict__ Wg, const float* __restrict__ Wv,
                       const float* __restrict__ Wo,
                       unsigned short* __restrict__ Wgh, unsigned short* __restrict__ Wvh,
                       unsigned short* __restrict__ Woh) {
  __shared__ int s_cnt[NEXP], s_off[NEXP], s_cur[NEXP];
  __shared__ int s_tn[T_TOK];
  int b = blockIdx.x;
  int tid = threadIdx.x;
  if (b == 0) {
    if (tid < NEXP) s_cnt[tid] = 0;
    for (int t = tid; t < T_TOK; t += 256) s_tn[t] = 0;
    __syncthreads();
    for (int t = tid; t < T_TOK; t += 256)
      for (int e = 0; e < NEXP; ++e)
        if (disp[t * NEXP + e] > 0.f) atomicAdd(&s_cnt[e], 1);
    __syncthreads();
    if (tid == 0) {
      int acc = 0;
      for (int e = 0; e < NEXP; ++e) { s_off[e] = acc; acc += s_cnt[e]; }
    }
    __syncthreads();
    if (tid < NEXP) {
      s_cur[tid] = s_off[tid];
      meta[tid] = s_cnt[tid];
      meta[NEXP + tid] = s_off[tid];
    }
    __syncthreads();
    for (int t = tid; t < T_TOK; t += 256)
      for (int e = 0; e < NEXP; ++e)
        if (disp[t * NEXP + e] > 0.f) {
          int p = atomicAdd(&s_cur[e], 1);
          row_token[p] = t;
          row_comb[p] = comb[t * NEXP + e];
          int sl = atomicAdd(&s_tn[t], 1);
          tok2pair[t * 2 + sl] = p;
        }
    __syncthreads();
    if (tid == 0) {
      int nt = 0;
      for (int e = 0; e < NEXP; ++e)
        for (int m0 = 0; m0 < s_cnt[e]; m0 += 128)
          meta[17 + nt++] = (e << 16) | (m0 >> 7);
      meta[16] = nt;
    }
    return;
  }
  // conversion blocks: 32768 fp32 elems each (16 chunks of 2048)
  int idx = b - 1;
  const float* src;
  unsigned short* dst;
  if (idx < 48)        { src = X;  dst = Xb;  }
  else if (idx < 624)  { src = Wg; dst = Wgh; idx -= 48;   }
  else if (idx < 1200) { src = Wv; dst = Wvh; idx -= 624;  }
  else                 { src = Wo; dst = Woh; idx -= 1200; }
  size_t base = (size_t)idx * 32768 + (size_t)tid * 8;
#pragma unroll
  for (int g = 0; g < 4; ++g) {
    float4 va[4], vb[4];
#pragma unroll
    for (int u = 0; u < 4; ++u) {        // 8 loads in flight (128 B/lane)
      size_t i = base + (size_t)(g * 4 + u) * 2048;
      va[u] = *(const float4*)(src + i);
      vb[u] = *(const float4*)(src + i + 4);
    }
#pragma unroll
    for (int u = 0; u < 4; ++u) {
      size_t i = base + (size_t)(g * 4 + u) * 2048;
      unsigned short r[8];
      r[0]=f2bf(va[u].x); r[1]=f2bf(va[u].y); r[2]=f2bf(va[u].z); r[3]=f2bf(va[u].w);
      r[4]=f2bf(vb[u].x); r[5]=f2bf(vb[u].y); r[6]=f2bf(vb[u].z); r[7]=f2bf(vb[u].w);
      *(uint4*)(dst + i) = *(uint4*)r;
    }
  }
}

// ------- GEMM 1 fused: u = gelu(X@Wg^T) * (X@Wv^T) -> bf16 (P,H) -------
// WBF=1: bf16 weights (r3-proven: gv 142->98us). Strip-affinity XCD remap
// (r4-proven: FETCH 338->102MB): all m-tiles of one (e, n-strip) weight
// strip land on the same XCD, schedule-adjacent.
template<int WBF>
__global__ __launch_bounds__(256, 2) void k_gemm_gv_t(
    const unsigned short* __restrict__ Xb,  // (T_TOK, DIM) bf16
    const float* __restrict__ Wg,           // (NEXP, HDIM, DIM) fp32
    const float* __restrict__ Wv,
    const unsigned short* __restrict__ Wgh, // (NEXP, HDIM, DIM) bf16
    const unsigned short* __restrict__ Wvh,
    const int* __restrict__ meta,
    const int* __restrict__ row_token,
    unsigned short* __restrict__ ubuf)      // (MAXP, HDIM) bf16
{
  int blk = blockIdx.x;                     // 960 = 8 xcd * 3 strips * 40 tiles
  int xc = blk & 7, slot = blk >> 3;
  int nt = xc + 8 * (slot / NTILE_MAX);     // n-strip pinned to xcd
  int t  = slot % NTILE_MAX;
  if (t >= meta[16]) return;
  int tv = meta[17 + t];
  int e = tv >> 16, m0 = (tv & 0xffff) << 7;
  int cnt = meta[e], off = meta[NEXP + e];
  int n0 = nt * 128;

  __shared__ unsigned short As[128 * LDST];
  __shared__ unsigned short Bgs[128 * LDST];
  __shared__ unsigned short Bvs[128 * LDST];

  int tid = threadIdx.x;
  int wid = tid >> 6, lane = tid & 63;
  int wm = (wid >> 1) * 64, wn = (wid & 1) * 64;
  int lr = lane & 15, quad = lane >> 4;

  int a_tok[2];
#pragma unroll
  for (int r = 0; r < 2; ++r) {
    int row = (tid + 256 * r) >> 2;
    int gr = m0 + row; if (gr >= cnt) gr = cnt - 1;
    a_tok[r] = row_token[off + gr];
  }

  const float* Wgb = Wg + (size_t)e * ((size_t)HDIM * DIM);
  const float* Wvb = Wv + (size_t)e * ((size_t)HDIM * DIM);
  const unsigned short* Wghb = Wgh + (size_t)e * ((size_t)HDIM * DIM);
  const unsigned short* Wvhb = Wvh + (size_t)e * ((size_t)HDIM * DIM);

  f32x4 zero4 = {0.f, 0.f, 0.f, 0.f};
  f32x4 accg[4][4], accv[4][4];
#pragma unroll
  for (int i = 0; i < 4; ++i)
#pragma unroll
    for (int j = 0; j < 4; ++j) { accg[i][j] = zero4; accv[i][j] = zero4; }

  for (int k0 = 0; k0 < DIM; k0 += 32) {
    __syncthreads();
#pragma unroll
    for (int r = 0; r < 2; ++r) {
      int c2 = tid + 256 * r;
      int row = c2 >> 2, sub = c2 & 3;
      uint4 av = *(const uint4*)(Xb + (size_t)a_tok[r] * DIM + k0 + sub * 8);
      *(uint4*)(&As[row * LDST + sub * 8]) = av;
    }
    if constexpr (WBF) {
#pragma unroll
      for (int r = 0; r < 2; ++r) {
        int c2 = tid + 256 * r;
        int row = c2 >> 2, sub = c2 & 3;
        uint4 gv = *(const uint4*)(Wghb + (size_t)(n0 + row) * DIM + k0 + sub * 8);
        *(uint4*)(&Bgs[row * LDST + sub * 8]) = gv;
        uint4 vv = *(const uint4*)(Wvhb + (size_t)(n0 + row) * DIM + k0 + sub * 8);
        *(uint4*)(&Bvs[row * LDST + sub * 8]) = vv;
      }
    } else {
#pragma unroll
      for (int r = 0; r < 4; ++r) {
        int c2 = tid + 256 * r;
        int row = c2 >> 3, c4 = c2 & 7;
        float4 gv = *(const float4*)(Wgb + (size_t)(n0 + row) * DIM + k0 + c4 * 4);
        ushort4 gp;
        gp.x = f2bf(gv.x); gp.y = f2bf(gv.y); gp.z = f2bf(gv.z); gp.w = f2bf(gv.w);
        *(ushort4*)(&Bgs[row * LDST + c4 * 4]) = gp;
        float4 vv = *(const float4*)(Wvb + (size_t)(n0 + row) * DIM + k0 + c4 * 4);
        ushort4 vp;
        vp.x = f2bf(vv.x); vp.y = f2bf(vv.y); vp.z = f2bf(vv.z); vp.w = f2bf(vv.w);
        *(ushort4*)(&Bvs[row * LDST + c4 * 4]) = vp;
      }
    }
    __syncthreads();
    bfrag a[4], bg[4], bv[4];
#pragma unroll
    for (int i = 0; i < 4; ++i)
      a[i] = *(const bfrag*)(&As[(wm + i * 16 + lr) * LDST + quad * 8]);
#pragma unroll
    for (int j = 0; j < 4; ++j) {
      bg[j] = *(const bfrag*)(&Bgs[(wn + j * 16 + lr) * LDST + quad * 8]);
      bv[j] = *(const bfrag*)(&Bvs[(wn + j * 16 + lr) * LDST + quad * 8]);
    }
#pragma unroll
    for (int i = 0; i < 4; ++i)
#pragma unroll
      for (int j = 0; j < 4; ++j) {
        accg[i][j] = __builtin_amdgcn_mfma_f32_16x16x32_bf16(a[i], bg[j], accg[i][j], 0, 0, 0);
        accv[i][j] = __builtin_amdgcn_mfma_f32_16x16x32_bf16(a[i], bv[j], accv[i][j], 0, 0, 0);
      }
  }

  // epilogue: gelu_exact(g)*v on fp32 accumulators
#pragma unroll
  for (int i = 0; i < 4; ++i)
#pragma unroll
    for (int rg = 0; rg < 4; ++rg) {
      int gr = m0 + wm + i * 16 + quad * 4 + rg;
      if (gr < cnt) {
        size_t base = (size_t)(off + gr) * HDIM + n0 + wn;
#pragma unroll
        for (int j = 0; j < 4; ++j) {
          float g = accg[i][j][rg];
          float v = accv[i][j][rg];
          float u = 0.5f * g * (1.0f + erff(g * 0.70710678118654752f)) * v;
          ubuf[base + j * 16 + lr] = f2bf(u);
        }
      }
    }
}

// ------- GEMM 2: u @ Wo^T, split-K x4, strip-affinity remap over (nt,ks).
//         mode 0: store w-scaled partials; mode 1: atomicAdd fallback. -------
template<int WBF>
__global__ __launch_bounds__(256, 2) void k_gemm_out_t(
    const unsigned short* __restrict__ U,  // (MAXP, HDIM) bf16
    const float* __restrict__ Wo,          // (NEXP, DIM, HDIM) fp32
    const unsigned short* __restrict__ Woh,// (NEXP, DIM, HDIM) bf16
    const float* __restrict__ scale,
    const int* __restrict__ meta,
    const int* __restrict__ row_token,
    const float* __restrict__ row_comb,
    float* __restrict__ partial,           // (4, MAXP, DIM)
    float* __restrict__ out,               // (T_TOK, DIM)
    int mode)
{
  int blk = blockIdx.x;                    // 960 = 8 xcd * 3 strips * 40 tiles
  int xc = blk & 7, slot = blk >> 3;
  int sidx = xc + 8 * (slot / NTILE_MAX);  // 0..23 strip index = (nt, ks)
  int nt = sidx % 6, ks = sidx / 6;
  int t = slot % NTILE_MAX;
  if (t >= meta[16]) return;
  int tv = meta[17 + t];
  int e = tv >> 16, m0 = (tv & 0xffff) << 7;
  int cnt = meta[e], off = meta[NEXP + e];
  int n0 = nt * 128;
  int kbase = ks * (HDIM / 4);

  __shared__ unsigned short As[128 * LDST];
  __shared__ unsigned short Bs[128 * LDST];

  int tid = threadIdx.x;
  int wid = tid >> 6, lane = tid & 63;
  int wm = (wid >> 1) * 64, wn = (wid & 1) * 64;
  int lr = lane & 15, quad = lane >> 4;

  int a_grow[2];
#pragma unroll
  for (int r = 0; r < 2; ++r) {
    int row = (tid + 256 * r) >> 2;
    int gr = m0 + row; if (gr >= cnt) gr = cnt - 1;
    a_grow[r] = off + gr;
  }

  const float* Wb = Wo + (size_t)e * ((size_t)DIM * HDIM);
  const unsigned short* Wbh = Woh + (size_t)e * ((size_t)DIM * HDIM);

  f32x4 zero4 = {0.f, 0.f, 0.f, 0.f};
  f32x4 acc[4][4];
#pragma unroll
  for (int i = 0; i < 4; ++i)
#pragma unroll
    for (int j = 0; j < 4; ++j) acc[i][j] = zero4;

  for (int kk = 0; kk < HDIM / 4; kk += 32) {
    int k0 = kbase + kk;
    __syncthreads();
#pragma unroll
    for (int r = 0; r < 2; ++r) {
      int c2 = tid + 256 * r;
      int row = c2 >> 2, sub = c2 & 3;
      uint4 av = *(const uint4*)(U + (size_t)a_grow[r] * HDIM + k0 + sub * 8);
      *(uint4*)(&As[row * LDST + sub * 8]) = av;
    }
    if constexpr (WBF) {
#pragma unroll
      for (int r = 0; r < 2; ++r) {
        int c2 = tid + 256 * r;
        int row = c2 >> 2, sub = c2 & 3;
        uint4 bv = *(const uint4*)(Wbh + (size_t)(n0 + row) * HDIM + k0 + sub * 8);
        *(uint4*)(&Bs[row * LDST + sub * 8]) = bv;
      }
    } else {
#pragma unroll
      for (int r = 0; r < 4; ++r) {
        int c2 = tid + 256 * r;
        int row = c2 >> 3, c4 = c2 & 7;
        float4 bvv = *(const float4*)(Wb + (size_t)(n0 + row) * HDIM + k0 + c4 * 4);
        ushort4 bp;
        bp.x = f2bf(bvv.x); bp.y = f2bf(bvv.y); bp.z = f2bf(bvv.z); bp.w = f2bf(bvv.w);
        *(ushort4*)(&Bs[row * LDST + c4 * 4]) = bp;
      }
    }
    __syncthreads();
    bfrag a[4], b[4];
#pragma unroll
    for (int i = 0; i < 4; ++i)
      a[i] = *(const bfrag*)(&As[(wm + i * 16 + lr) * LDST + quad * 8]);
#pragma unroll
    for (int j = 0; j < 4; ++j)
      b[j] = *(const bfrag*)(&Bs[(wn + j * 16 + lr) * LDST + quad * 8]);
#pragma unroll
    for (int i = 0; i < 4; ++i)
#pragma unroll
      for (int j = 0; j < 4; ++j)
        acc[i][j] = __builtin_amdgcn_mfma_f32_16x16x32_bf16(a[i], b[j], acc[i][j], 0, 0, 0);
  }

  float sc = scale[e];
#pragma unroll
  for (int i = 0; i < 4; ++i)
#pragma unroll
    for (int rg = 0; rg < 4; ++rg) {
      int gr = m0 + wm + i * 16 + quad * 4 + rg;
      if (gr < cnt) {
        int grow = off + gr;
        float w = row_comb[grow] * sc;
        if (mode == 0) {
          float* pb = partial + ((size_t)ks * MAXP + grow) * DIM + n0 + wn;
#pragma unroll
          for (int j = 0; j < 4; ++j)
            pb[j * 16 + lr] = acc[i][j][rg] * w;
        } else {
          int tok = row_token[grow];
          float* ob = out + (size_t)tok * DIM + n0 + wn;
#pragma unroll
          for (int j = 0; j < 4; ++j)
            atomicAdd(ob + j * 16 + lr, acc[i][j][rg] * w);
        }
      }
    }
}

// ---------------- combine: out[t] = sum over 2 pairs x 4 K-splits ----------------
__global__ void k_combine(const float* __restrict__ partial,
                          const int* __restrict__ tok2pair,
                          float* __restrict__ out) {
  int idx = blockIdx.x * 256 + threadIdx.x;   // 2048 * 192 = 393216
  int t = idx / 192, d4 = idx % 192;
  int p0 = tok2pair[t * 2], p1 = tok2pair[t * 2 + 1];
  float sx = 0.f, sy = 0.f, sz = 0.f, sw = 0.f;
#pragma unroll
  for (int ks = 0; ks < 4; ++ks) {
    float4 a = *(const float4*)(partial + ((size_t)ks * MAXP + p0) * DIM + d4 * 4);
    float4 b = *(const float4*)(partial + ((size_t)ks * MAXP + p1) * DIM + d4 * 4);
    sx += a.x + b.x; sy += a.y + b.y; sz += a.z + b.z; sw += a.w + b.w;
  }
  float4 r; r.x = sx; r.y = sy; r.z = sz; r.w = sw;
  *(float4*)(out + (size_t)t * DIM + d4 * 4) = r;
}

extern "C" void kernel_launch(void* const* d_in, const int* in_sizes, int n_in,
                              void* d_out, int out_size, void* d_ws, size_t ws_size,
                              hipStream_t stream) {
  const float* tokens = (const float*)d_in[0];
  const float* disp   = (const float*)d_in[1];
  const float* comb   = (const float*)d_in[2];
  const float* Wg     = (const float*)d_in[3];
  const float* Wv     = (const float*)d_in[4];
  const float* Wo     = (const float*)d_in[5];
  const float* scale  = (const float*)d_in[6];
  float* out = (float*)d_out;

  char* ws = (char*)d_ws;
  int*   meta      = (int*)ws;                        // 57 ints
  int*   row_token = (int*)(ws + 16384);
  float* row_comb  = (float*)(ws + 32768);
  int*   tok2pair  = (int*)(ws + 49152);
  unsigned short* Xb   = (unsigned short*)(ws + (1ull << 20));          // 3 MB
  unsigned short* ubuf = (unsigned short*)(ws + (5ull << 20));          // 24 MB
  float* partial = (float*)(ws + (32ull << 20));                        // 48 MB

  // bf16 weight copies: each tensor 8*3072*768*2 B = 36 MiB.
  const size_t need_partial = (32ull << 20) + (size_t)4 * MAXP * DIM * sizeof(float); // 80 MiB
  const size_t need_full = 188ull << 20;   // 80 front + 3x36 weights
  const size_t need_mid  = 140ull << 20;   // 32 front (no partial) + 3x36

  int wbf, mode;
  unsigned short *Wgh = nullptr, *Wvh = nullptr, *Woh = nullptr;
  if (ws_size >= need_full) {
    wbf = 1; mode = 0;
    Wgh = (unsigned short*)(ws + (80ull  << 20));
    Wvh = (unsigned short*)(ws + (116ull << 20));
    Woh = (unsigned short*)(ws + (152ull << 20));
  } else if (ws_size >= need_mid) {
    wbf = 1; mode = 1;   // weights overlap partial space -> atomic combine
    Wgh = (unsigned short*)(ws + (32ull  << 20));
    Wvh = (unsigned short*)(ws + (68ull  << 20));
    Woh = (unsigned short*)(ws + (104ull << 20));
  } else {
    wbf = 0;
    mode = (ws_size >= need_partial) ? 0 : 1;
    Wgh = Wvh = Woh = (unsigned short*)Xb;  // unused by WBF=0 path
  }

  // fused routing + conversions (route block hides under conversion stream)
  // conversion blocks: 48 (X) + 3*576 (weights) = 1776 fat blocks
  int prep_grid = wbf ? (1 + 48 + 3 * 576) : (1 + 48);
  hipLaunchKernelGGL(k_prep, dim3(prep_grid), dim3(256), 0, stream,
                     disp, comb, meta, row_comb, row_token, tok2pair,
                     tokens, Xb, Wg, Wv, Wo, Wgh, Wvh, Woh);

  if (wbf)
    hipLaunchKernelGGL(HIP_KERNEL_NAME(k_gemm_gv_t<1>), dim3(NTILE_MAX * 24), dim3(256), 0, stream,
                       Xb, Wg, Wv, Wgh, Wvh, meta, row_token, ubuf);
  else
    hipLaunchKernelGGL(HIP_KERNEL_NAME(k_gemm_gv_t<0>), dim3(NTILE_MAX * 24), dim3(256), 0, stream,
                       Xb, Wg, Wv, Wgh, Wvh, meta, row_token, ubuf);

  if (mode == 1)
    hipMemsetAsync(d_out, 0, (size_t)out_size * sizeof(float), stream);

  if (wbf)
    hipLaunchKernelGGL(HIP_KERNEL_NAME(k_gemm_out_t<1>), dim3(NTILE_MAX * 6 * 4), dim3(256), 0, stream,
                       ubuf, Wo, Woh, scale, meta, row_token, row_comb, partial, out, mode);
  else
    hipLaunchKernelGGL(HIP_KERNEL_NAME(k_gemm_out_t<0>), dim3(NTILE_MAX * 6 * 4), dim3(256), 0, stream,
                       ubuf, Wo, Woh, scale, meta, row_token, row_comb, partial, out, mode);

  if (mode == 0)
    hipLaunchKernelGGL(k_combine, dim3((T_TOK * DIM / 4) / 256), dim3(256), 0, stream,
                       partial, tok2pair, out);
}

// Round 8
// 401.076 us; speedup vs baseline: 1.0224x; 1.0224x over previous
//
#include <hip/hip_runtime.h>
#include <hip/hip_bf16.h>
#include <math.h>

// ExpertPool: B=2,N=1024 -> T=2048 tokens, D=768, E=8, H=3072, top-K=2
#define T_TOK 2048
#define DIM   768
#define NEXP  8
#define HDIM  3072
#define MAXP  (T_TOK * 2)   // exactly 4096 (token,expert) pairs
#define LDST  40            // LDS row stride in ushorts (80 B)
#define NTILE_MAX 40        // sum ceil(cnt_e/128) <= 39

typedef __attribute__((ext_vector_type(8))) short bfrag;   // 8 bf16 (4 VGPRs)
typedef __attribute__((ext_vector_type(4))) float f32x4;   // MFMA C/D

__device__ __forceinline__ unsigned short f2bf(float f) {
  union { float f; unsigned int u; } x; x.f = f;
  unsigned int r = x.u + 0x7fffu + ((x.u >> 16) & 1u);  // RNE
  return (unsigned short)(r >> 16);
}

// ---- fused prep: block 0 = routing (ballot-based, atomic-free, ~10us);
//      blocks 1.. = fp32->bf16 streaming convert (r7 fat-block form).
//      r7 lesson: converter grid shape is irrelevant (125us both ways) ->
//      hypothesis: the old atomic-storm routing block WAS the critical path.
__global__ void k_prep(const float* __restrict__ disp,
                       const float* __restrict__ comb,
                       int* __restrict__ meta,        // [0..7]=cnt [8..15]=off [16]=ntiles [17..56]=tiles
                       float* __restrict__ row_comb,
                       int* __restrict__ row_token,
                       int* __restrict__ tok2pair,    // (T_TOK,2)
                       const float* __restrict__ X, unsigned short* __restrict__ Xb,
                       const float* __restrict__ Wg, const float* __restrict__ Wv,
                       const float* __restrict__ Wo,
                       unsigned short* __restrict__ Wgh, unsigned short* __restrict__ Wvh,
                       unsigned short* __restrict__ Woh) {
  __shared__ int s_wsum[4];
  int b = blockIdx.x;
  int tid = threadIdx.x;
  if (b == 0) {
    // Expert-outer single pass. Token t is always handled by thread (t&255),
    // so per-token slot counters live in registers (tn[it], unrolled-static).
    // Position p = run + waves-before + lane-prefix; run is recomputed
    // redundantly by every thread (identical value, no LDS counter).
    int lane = tid & 63, wid = tid >> 6;
    unsigned long long lmask = (1ull << lane) - 1ull;
    int tn0 = 0, tn1 = 0, tn2 = 0, tn3 = 0, tn4 = 0, tn5 = 0, tn6 = 0, tn7 = 0;
    int run = 0;
#pragma unroll
    for (int e = 0; e < NEXP; ++e) {
      int off_e = run;
#pragma unroll
      for (int it = 0; it < 8; ++it) {
        int t = it * 256 + tid;
        bool pos = disp[t * NEXP + e] > 0.f;
        unsigned long long m = __ballot(pos);
        int lpfx = (int)__popcll(m & lmask);
        int wcnt = (int)__popcll(m);
        if (lane == 0) s_wsum[wid] = wcnt;
        __syncthreads();
        int w0 = s_wsum[0], w1 = s_wsum[1], w2 = s_wsum[2], w3 = s_wsum[3];
        int wbase = run + (wid > 0 ? w0 : 0) + (wid > 1 ? w1 : 0) + (wid > 2 ? w2 : 0);
        if (pos) {
          int p = wbase + lpfx;
          row_token[p] = t;
          row_comb[p] = comb[t * NEXP + e];
          int sl;
          if      (it == 0) { sl = tn0++; }
          else if (it == 1) { sl = tn1++; }
          else if (it == 2) { sl = tn2++; }
          else if (it == 3) { sl = tn3++; }
          else if (it == 4) { sl = tn4++; }
          else if (it == 5) { sl = tn5++; }
          else if (it == 6) { sl = tn6++; }
          else              { sl = tn7++; }
          tok2pair[t * 2 + sl] = p;
        }
        run += w0 + w1 + w2 + w3;
        __syncthreads();
      }
      if (tid == 0) { meta[e] = run - off_e; meta[NEXP + e] = off_e; }
    }
    if (tid == 0) {
      int nt = 0;
      for (int e = 0; e < NEXP; ++e) {
        int cnt = meta[e];                  // own writes, coherent in-thread
        for (int m0 = 0; m0 < cnt; m0 += 128)
          meta[17 + nt++] = (e << 16) | (m0 >> 7);
      }
      meta[16] = nt;
    }
    return;
  }
  // conversion blocks: 32768 fp32 elems each (16 chunks of 2048)
  int idx = b - 1;
  const float* src;
  unsigned short* dst;
  if (idx < 48)        { src = X;  dst = Xb;  }
  else if (idx < 624)  { src = Wg; dst = Wgh; idx -= 48;   }
  else if (idx < 1200) { src = Wv; dst = Wvh; idx -= 624;  }
  else                 { src = Wo; dst = Woh; idx -= 1200; }
  size_t base = (size_t)idx * 32768 + (size_t)tid * 8;
#pragma unroll
  for (int g = 0; g < 4; ++g) {
    float4 va[4], vb[4];
#pragma unroll
    for (int u = 0; u < 4; ++u) {        // 8 loads in flight (128 B/lane)
      size_t i = base + (size_t)(g * 4 + u) * 2048;
      va[u] = *(const float4*)(src + i);
      vb[u] = *(const float4*)(src + i + 4);
    }
#pragma unroll
    for (int u = 0; u < 4; ++u) {
      size_t i = base + (size_t)(g * 4 + u) * 2048;
      unsigned short r[8];
      r[0]=f2bf(va[u].x); r[1]=f2bf(va[u].y); r[2]=f2bf(va[u].z); r[3]=f2bf(va[u].w);
      r[4]=f2bf(vb[u].x); r[5]=f2bf(vb[u].y); r[6]=f2bf(vb[u].z); r[7]=f2bf(vb[u].w);
      *(uint4*)(dst + i) = *(uint4*)r;
    }
  }
}

// ------- GEMM 1 fused: u = gelu(X@Wg^T) * (X@Wv^T) -> bf16 (P,H) -------
// WBF=1: bf16 weights (r3-proven: gv 142->98us). Strip-affinity XCD remap
// (r4-proven: FETCH 338->102MB): all m-tiles of one (e, n-strip) weight
// strip land on the same XCD, schedule-adjacent.
template<int WBF>
__global__ __launch_bounds__(256, 2) void k_gemm_gv_t(
    const unsigned short* __restrict__ Xb,  // (T_TOK, DIM) bf16
    const float* __restrict__ Wg,           // (NEXP, HDIM, DIM) fp32
    const float* __restrict__ Wv,
    const unsigned short* __restrict__ Wgh, // (NEXP, HDIM, DIM) bf16
    const unsigned short* __restrict__ Wvh,
    const int* __restrict__ meta,
    const int* __restrict__ row_token,
    unsigned short* __restrict__ ubuf)      // (MAXP, HDIM) bf16
{
  int blk = blockIdx.x;                     // 960 = 8 xcd * 3 strips * 40 tiles
  int xc = blk & 7, slot = blk >> 3;
  int nt = xc + 8 * (slot / NTILE_MAX);     // n-strip pinned to xcd
  int t  = slot % NTILE_MAX;
  if (t >= meta[16]) return;
  int tv = meta[17 + t];
  int e = tv >> 16, m0 = (tv & 0xffff) << 7;
  int cnt = meta[e], off = meta[NEXP + e];
  int n0 = nt * 128;

  __shared__ unsigned short As[128 * LDST];
  __shared__ unsigned short Bgs[128 * LDST];
  __shared__ unsigned short Bvs[128 * LDST];

  int tid = threadIdx.x;
  int wid = tid >> 6, lane = tid & 63;
  int wm = (wid >> 1) * 64, wn = (wid & 1) * 64;
  int lr = lane & 15, quad = lane >> 4;

  int a_tok[2];
#pragma unroll
  for (int r = 0; r < 2; ++r) {
    int row = (tid + 256 * r) >> 2;
    int gr = m0 + row; if (gr >= cnt) gr = cnt - 1;
    a_tok[r] = row_token[off + gr];
  }

  const float* Wgb = Wg + (size_t)e * ((size_t)HDIM * DIM);
  const float* Wvb = Wv + (size_t)e * ((size_t)HDIM * DIM);
  const unsigned short* Wghb = Wgh + (size_t)e * ((size_t)HDIM * DIM);
  const unsigned short* Wvhb = Wvh + (size_t)e * ((size_t)HDIM * DIM);

  f32x4 zero4 = {0.f, 0.f, 0.f, 0.f};
  f32x4 accg[4][4], accv[4][4];
#pragma unroll
  for (int i = 0; i < 4; ++i)
#pragma unroll
    for (int j = 0; j < 4; ++j) { accg[i][j] = zero4; accv[i][j] = zero4; }

  for (int k0 = 0; k0 < DIM; k0 += 32) {
    __syncthreads();
#pragma unroll
    for (int r = 0; r < 2; ++r) {
      int c2 = tid + 256 * r;
      int row = c2 >> 2, sub = c2 & 3;
      uint4 av = *(const uint4*)(Xb + (size_t)a_tok[r] * DIM + k0 + sub * 8);
      *(uint4*)(&As[row * LDST + sub * 8]) = av;
    }
    if constexpr (WBF) {
#pragma unroll
      for (int r = 0; r < 2; ++r) {
        int c2 = tid + 256 * r;
        int row = c2 >> 2, sub = c2 & 3;
        uint4 gv = *(const uint4*)(Wghb + (size_t)(n0 + row) * DIM + k0 + sub * 8);
        *(uint4*)(&Bgs[row * LDST + sub * 8]) = gv;
        uint4 vv = *(const uint4*)(Wvhb + (size_t)(n0 + row) * DIM + k0 + sub * 8);
        *(uint4*)(&Bvs[row * LDST + sub * 8]) = vv;
      }
    } else {
#pragma unroll
      for (int r = 0; r < 4; ++r) {
        int c2 = tid + 256 * r;
        int row = c2 >> 3, c4 = c2 & 7;
        float4 gv = *(const float4*)(Wgb + (size_t)(n0 + row) * DIM + k0 + c4 * 4);
        ushort4 gp;
        gp.x = f2bf(gv.x); gp.y = f2bf(gv.y); gp.z = f2bf(gv.z); gp.w = f2bf(gv.w);
        *(ushort4*)(&Bgs[row * LDST + c4 * 4]) = gp;
        float4 vv = *(const float4*)(Wvb + (size_t)(n0 + row) * DIM + k0 + c4 * 4);
        ushort4 vp;
        vp.x = f2bf(vv.x); vp.y = f2bf(vv.y); vp.z = f2bf(vv.z); vp.w = f2bf(vv.w);
        *(ushort4*)(&Bvs[row * LDST + c4 * 4]) = vp;
      }
    }
    __syncthreads();
    bfrag a[4], bg[4], bv[4];
#pragma unroll
    for (int i = 0; i < 4; ++i)
      a[i] = *(const bfrag*)(&As[(wm + i * 16 + lr) * LDST + quad * 8]);
#pragma unroll
    for (int j = 0; j < 4; ++j) {
      bg[j] = *(const bfrag*)(&Bgs[(wn + j * 16 + lr) * LDST + quad * 8]);
      bv[j] = *(const bfrag*)(&Bvs[(wn + j * 16 + lr) * LDST + quad * 8]);
    }
#pragma unroll
    for (int i = 0; i < 4; ++i)
#pragma unroll
      for (int j = 0; j < 4; ++j) {
        accg[i][j] = __builtin_amdgcn_mfma_f32_16x16x32_bf16(a[i], bg[j], accg[i][j], 0, 0, 0);
        accv[i][j] = __builtin_amdgcn_mfma_f32_16x16x32_bf16(a[i], bv[j], accv[i][j], 0, 0, 0);
      }
  }

  // epilogue: gelu_exact(g)*v on fp32 accumulators
#pragma unroll
  for (int i = 0; i < 4; ++i)
#pragma unroll
    for (int rg = 0; rg < 4; ++rg) {
      int gr = m0 + wm + i * 16 + quad * 4 + rg;
      if (gr < cnt) {
        size_t base = (size_t)(off + gr) * HDIM + n0 + wn;
#pragma unroll
        for (int j = 0; j < 4; ++j) {
          float g = accg[i][j][rg];
          float v = accv[i][j][rg];
          float u = 0.5f * g * (1.0f + erff(g * 0.70710678118654752f)) * v;
          ubuf[base + j * 16 + lr] = f2bf(u);
        }
      }
    }
}

// ------- GEMM 2: u @ Wo^T, split-K x4, strip-affinity remap over (nt,ks).
//         mode 0: store w-scaled partials; mode 1: atomicAdd fallback. -------
template<int WBF>
__global__ __launch_bounds__(256, 2) void k_gemm_out_t(
    const unsigned short* __restrict__ U,  // (MAXP, HDIM) bf16
    const float* __restrict__ Wo,          // (NEXP, DIM, HDIM) fp32
    const unsigned short* __restrict__ Woh,// (NEXP, DIM, HDIM) bf16
    const float* __restrict__ scale,
    const int* __restrict__ meta,
    const int* __restrict__ row_token,
    const float* __restrict__ row_comb,
    float* __restrict__ partial,           // (4, MAXP, DIM)
    float* __restrict__ out,               // (T_TOK, DIM)
    int mode)
{
  int blk = blockIdx.x;                    // 960 = 8 xcd * 3 strips * 40 tiles
  int xc = blk & 7, slot = blk >> 3;
  int sidx = xc + 8 * (slot / NTILE_MAX);  // 0..23 strip index = (nt, ks)
  int nt = sidx % 6, ks = sidx / 6;
  int t = slot % NTILE_MAX;
  if (t >= meta[16]) return;
  int tv = meta[17 + t];
  int e = tv >> 16, m0 = (tv & 0xffff) << 7;
  int cnt = meta[e], off = meta[NEXP + e];
  int n0 = nt * 128;
  int kbase = ks * (HDIM / 4);

  __shared__ unsigned short As[128 * LDST];
  __shared__ unsigned short Bs[128 * LDST];

  int tid = threadIdx.x;
  int wid = tid >> 6, lane = tid & 63;
  int wm = (wid >> 1) * 64, wn = (wid & 1) * 64;
  int lr = lane & 15, quad = lane >> 4;

  int a_grow[2];
#pragma unroll
  for (int r = 0; r < 2; ++r) {
    int row = (tid + 256 * r) >> 2;
    int gr = m0 + row; if (gr >= cnt) gr = cnt - 1;
    a_grow[r] = off + gr;
  }

  const float* Wb = Wo + (size_t)e * ((size_t)DIM * HDIM);
  const unsigned short* Wbh = Woh + (size_t)e * ((size_t)DIM * HDIM);

  f32x4 zero4 = {0.f, 0.f, 0.f, 0.f};
  f32x4 acc[4][4];
#pragma unroll
  for (int i = 0; i < 4; ++i)
#pragma unroll
    for (int j = 0; j < 4; ++j) acc[i][j] = zero4;

  for (int kk = 0; kk < HDIM / 4; kk += 32) {
    int k0 = kbase + kk;
    __syncthreads();
#pragma unroll
    for (int r = 0; r < 2; ++r) {
      int c2 = tid + 256 * r;
      int row = c2 >> 2, sub = c2 & 3;
      uint4 av = *(const uint4*)(U + (size_t)a_grow[r] * HDIM + k0 + sub * 8);
      *(uint4*)(&As[row * LDST + sub * 8]) = av;
    }
    if constexpr (WBF) {
#pragma unroll
      for (int r = 0; r < 2; ++r) {
        int c2 = tid + 256 * r;
        int row = c2 >> 2, sub = c2 & 3;
        uint4 bv = *(const uint4*)(Wbh + (size_t)(n0 + row) * HDIM + k0 + sub * 8);
        *(uint4*)(&Bs[row * LDST + sub * 8]) = bv;
      }
    } else {
#pragma unroll
      for (int r = 0; r < 4; ++r) {
        int c2 = tid + 256 * r;
        int row = c2 >> 3, c4 = c2 & 7;
        float4 bvv = *(const float4*)(Wb + (size_t)(n0 + row) * HDIM + k0 + c4 * 4);
        ushort4 bp;
        bp.x = f2bf(bvv.x); bp.y = f2bf(bvv.y); bp.z = f2bf(bvv.z); bp.w = f2bf(bvv.w);
        *(ushort4*)(&Bs[row * LDST + c4 * 4]) = bp;
      }
    }
    __syncthreads();
    bfrag a[4], b[4];
#pragma unroll
    for (int i = 0; i < 4; ++i)
      a[i] = *(const bfrag*)(&As[(wm + i * 16 + lr) * LDST + quad * 8]);
#pragma unroll
    for (int j = 0; j < 4; ++j)
      b[j] = *(const bfrag*)(&Bs[(wn + j * 16 + lr) * LDST + quad * 8]);
#pragma unroll
    for (int i = 0; i < 4; ++i)
#pragma unroll
      for (int j = 0; j < 4; ++j)
        acc[i][j] = __builtin_amdgcn_mfma_f32_16x16x32_bf16(a[i], b[j], acc[i][j], 0, 0, 0);
  }

  float sc = scale[e];
#pragma unroll
  for (int i = 0; i < 4; ++i)
#pragma unroll
    for (int rg = 0; rg < 4; ++rg) {
      int gr = m0 + wm + i * 16 + quad * 4 + rg;
      if (gr < cnt) {
        int grow = off + gr;
        float w = row_comb[grow] * sc;
        if (mode == 0) {
          float* pb = partial + ((size_t)ks * MAXP + grow) * DIM + n0 + wn;
#pragma unroll
          for (int j = 0; j < 4; ++j)
            pb[j * 16 + lr] = acc[i][j][rg] * w;
        } else {
          int tok = row_token[grow];
          float* ob = out + (size_t)tok * DIM + n0 + wn;
#pragma unroll
          for (int j = 0; j < 4; ++j)
            atomicAdd(ob + j * 16 + lr, acc[i][j][rg] * w);
        }
      }
    }
}

// ---------------- combine: out[t] = sum over 2 pairs x 4 K-splits ----------------
__global__ void k_combine(const float* __restrict__ partial,
                          const int* __restrict__ tok2pair,
                          float* __restrict__ out) {
  int idx = blockIdx.x * 256 + threadIdx.x;   // 2048 * 192 = 393216
  int t = idx / 192, d4 = idx % 192;
  int p0 = tok2pair[t * 2], p1 = tok2pair[t * 2 + 1];
  float sx = 0.f, sy = 0.f, sz = 0.f, sw = 0.f;
#pragma unroll
  for (int ks = 0; ks < 4; ++ks) {
    float4 a = *(const float4*)(partial + ((size_t)ks * MAXP + p0) * DIM + d4 * 4);
    float4 b = *(const float4*)(partial + ((size_t)ks * MAXP + p1) * DIM + d4 * 4);
    sx += a.x + b.x; sy += a.y + b.y; sz += a.z + b.z; sw += a.w + b.w;
  }
  float4 r; r.x = sx; r.y = sy; r.z = sz; r.w = sw;
  *(float4*)(out + (size_t)t * DIM + d4 * 4) = r;
}

extern "C" void kernel_launch(void* const* d_in, const int* in_sizes, int n_in,
                              void* d_out, int out_size, void* d_ws, size_t ws_size,
                              hipStream_t stream) {
  const float* tokens = (const float*)d_in[0];
  const float* disp   = (const float*)d_in[1];
  const float* comb   = (const float*)d_in[2];
  const float* Wg     = (const float*)d_in[3];
  const float* Wv     = (const float*)d_in[4];
  const float* Wo     = (const float*)d_in[5];
  const float* scale  = (const float*)d_in[6];
  float* out = (float*)d_out;

  char* ws = (char*)d_ws;
  int*   meta      = (int*)ws;                        // 57 ints
  int*   row_token = (int*)(ws + 16384);
  float* row_comb  = (float*)(ws + 32768);
  int*   tok2pair  = (int*)(ws + 49152);
  unsigned short* Xb   = (unsigned short*)(ws + (1ull << 20));          // 3 MB
  unsigned short* ubuf = (unsigned short*)(ws + (5ull << 20));          // 24 MB
  float* partial = (float*)(ws + (32ull << 20));                        // 48 MB

  // bf16 weight copies: each tensor 8*3072*768*2 B = 36 MiB.
  const size_t need_partial = (32ull << 20) + (size_t)4 * MAXP * DIM * sizeof(float); // 80 MiB
  const size_t need_full = 188ull << 20;   // 80 front + 3x36 weights
  const size_t need_mid  = 140ull << 20;   // 32 front (no partial) + 3x36

  int wbf, mode;
  unsigned short *Wgh = nullptr, *Wvh = nullptr, *Woh = nullptr;
  if (ws_size >= need_full) {
    wbf = 1; mode = 0;
    Wgh = (unsigned short*)(ws + (80ull  << 20));
    Wvh = (unsigned short*)(ws + (116ull << 20));
    Woh = (unsigned short*)(ws + (152ull << 20));
  } else if (ws_size >= need_mid) {
    wbf = 1; mode = 1;   // weights overlap partial space -> atomic combine
    Wgh = (unsigned short*)(ws + (32ull  << 20));
    Wvh = (unsigned short*)(ws + (68ull  << 20));
    Woh = (unsigned short*)(ws + (104ull << 20));
  } else {
    wbf = 0;
    mode = (ws_size >= need_partial) ? 0 : 1;
    Wgh = Wvh = Woh = (unsigned short*)Xb;  // unused by WBF=0 path
  }

  // fused routing + conversions (route block hides under conversion stream)
  // conversion blocks: 48 (X) + 3*576 (weights) = 1776 fat blocks
  int prep_grid = wbf ? (1 + 48 + 3 * 576) : (1 + 48);
  hipLaunchKernelGGL(k_prep, dim3(prep_grid), dim3(256), 0, stream,
                     disp, comb, meta, row_comb, row_token, tok2pair,
                     tokens, Xb, Wg, Wv, Wo, Wgh, Wvh, Woh);

  if (wbf)
    hipLaunchKernelGGL(HIP_KERNEL_NAME(k_gemm_gv_t<1>), dim3(NTILE_MAX * 24), dim3(256), 0, stream,
                       Xb, Wg, Wv, Wgh, Wvh, meta, row_token, ubuf);
  else
    hipLaunchKernelGGL(HIP_KERNEL_NAME(k_gemm_gv_t<0>), dim3(NTILE_MAX * 24), dim3(256), 0, stream,
                       Xb, Wg, Wv, Wgh, Wvh, meta, row_token, ubuf);

  if (mode == 1)
    hipMemsetAsync(d_out, 0, (size_t)out_size * sizeof(float), stream);

  if (wbf)
    hipLaunchKernelGGL(HIP_KERNEL_NAME(k_gemm_out_t<1>), dim3(NTILE_MAX * 6 * 4), dim3(256), 0, stream,
                       ubuf, Wo, Woh, scale, meta, row_token, row_comb, partial, out, mode);
  else
    hipLaunchKernelGGL(HIP_KERNEL_NAME(k_gemm_out_t<0>), dim3(NTILE_MAX * 6 * 4), dim3(256), 0, stream,
                       ubuf, Wo, Woh, scale, meta, row_token, row_comb, partial, out, mode);

  if (mode == 0)
    hipLaunchKernelGGL(k_combine, dim3((T_TOK * DIM / 4) / 256), dim3(256), 0, stream,
                       partial, tok2pair, out);
}